// Round 5
// baseline (490.173 us; speedup 1.0000x reference)
//
#include <hip/hip_runtime.h>
#include <hip/hip_bf16.h>
#include <cmath>

// y = x[4096,8192] @ W[8192,8192]^T + b; avgpool16 -> gelu_tanh*2 -> rowmax
// Key algebra: avgpool over OUT features commutes with the GEMM:
//   pooled = x @ Wp^T  where Wp[g,:] = sum of W rows 16g..16g+15  (then /16 later)
// -> GEMM is 4096 x 512 x 8192 (16x fewer FLOPs than naive).
// x f32->bf16 conversion is fused into GEMM A-staging (reg-staged +
// v_cvt_pk_bf16_f32). This round: double-buffered LDS + prefetch-ahead
// (T3-minimum pipeline) so global loads have a full K-iter of latency cover.
#define M_DIM 4096
#define N_POOL 512
#define K_DIM 8192
#define KSPLIT 4
#define K_PER (K_DIM / KSPLIT)  // 2048

typedef __bf16 bf16x8 __attribute__((ext_vector_type(8)));
typedef float floatx4 __attribute__((ext_vector_type(4)));

__device__ __forceinline__ unsigned short f2bf(float f) {
  unsigned int u = __float_as_uint(f);
  return (unsigned short)((u + 0x7fffu + ((u >> 16) & 1u)) >> 16);  // RNE
}

// Prep: blocks [0,512) pool W rows (f32 accum -> bf16 Wp); block 512 pools bias.
__global__ __launch_bounds__(256) void prep_kernel(
    const float* __restrict__ W, unsigned short* __restrict__ Wp,
    const float* __restrict__ b, float* __restrict__ bpool) {
  int bid = blockIdx.x;
  if (bid < N_POOL) {
    int g = bid;
    const float* base = W + (size_t)g * 16 * K_DIM;
    ushort4* out = (ushort4*)(Wp + (size_t)g * K_DIM);
    for (int c4 = threadIdx.x; c4 < K_DIM / 4; c4 += blockDim.x) {
      float4 s = {0.f, 0.f, 0.f, 0.f};
#pragma unroll
      for (int j = 0; j < 16; ++j) {
        float4 v = ((const float4*)(base + (size_t)j * K_DIM))[c4];
        s.x += v.x; s.y += v.y; s.z += v.z; s.w += v.w;
      }
      ushort4 o;
      o.x = f2bf(s.x); o.y = f2bf(s.y); o.z = f2bf(s.z); o.w = f2bf(s.w);
      out[c4] = o;
    }
  } else {
    for (int g = threadIdx.x; g < N_POOL; g += blockDim.x) {
      float s = 0.f;
#pragma unroll
      for (int i = 0; i < 16; ++i) s += b[g * 16 + i];
      bpool[g] = s;
    }
  }
}

// Split-K GEMM: C_part[kz] = x[:, kz*2048:(kz+1)*2048] @ Wp[:, same]^T
// 128x128 tile, BK=64, 4 waves of 64x64, mfma_f32_16x16x32_bf16.
// A: reg-staged from f32 x (fused conversion, XOR-swizzled LDS image).
// B: global_load_lds width=16 with pre-swizzled global source.
// Double-buffered LDS; tile t+1 loads issued before tile t compute, so
// HBM latency hides under MFMA. One barrier per K-iter.
// 1D grid of 512, XCD-aware decode: kz pinned to an XCD pair so the
// per-kz Wp slice (1 MiB/XCD) is L2-resident.
__global__ __launch_bounds__(256) void gemm_splitk(
    const float* __restrict__ x,             // [4096][8192] f32
    const unsigned short* __restrict__ wp,   // [512][8192] bf16
    float* __restrict__ part)                // [KSPLIT][4096][512] fp32
{
  __shared__ __align__(16) unsigned short As[2][128 * 64];
  __shared__ __align__(16) unsigned short Bs[2][128 * 64];

  const int tid = threadIdx.x;
  const int L = tid & 63;
  const int w = tid >> 6;
  const int wm = w & 1, wn = w >> 1;
  const int lane15 = L & 15, quad = L >> 4;

  // id -> (kz, bn, bm): xcd = id%8 (HW round-robin), 2 XCDs per kz value.
  const int id = blockIdx.x;
  const int xcd = id & 7;
  const int c = id >> 3;               // 0..63 within XCD
  const int kz = xcd >> 1;             // 0..3
  const int j = (c << 1) | (xcd & 1);  // 0..127 within kz
  const int bn = j & 3, bm = j >> 2;

  const int srow = w * 32 + (L >> 3);          // staging row (i adds 8)
  const int gcol8 = (L & 7) ^ ((L >> 3) & 7);  // swizzled global chunk
  const float* gx = x + (size_t)(bm * 128 + srow) * K_DIM + kz * K_PER + gcol8 * 8;
  const unsigned short* gb = wp + (size_t)(bn * 128 + srow) * K_DIM + kz * K_PER + gcol8 * 8;
  const int aoff = srow * 64 + (L & 7) * 8;    // A LDS write offset (shorts)
  const int boff = (w * 32) * 64;              // B DMA base offset (shorts)

  floatx4 acc[4][4];
#pragma unroll
  for (int t = 0; t < 4; ++t)
#pragma unroll
    for (int u = 0; u < 4; ++u) acc[t][u] = (floatx4)0.f;

  // ---- prologue: stage tile 0 into buffer 0 ----
  {
    float4 fa[4], fb4[4];
#pragma unroll
    for (int i = 0; i < 4; ++i) {
      const float4* p = (const float4*)(gx + (size_t)(i * 8) * K_DIM);
      fa[i] = p[0];
      fb4[i] = p[1];
    }
#pragma unroll
    for (int i = 0; i < 4; ++i) {
      __builtin_amdgcn_global_load_lds(
          (const __attribute__((address_space(1))) void*)(gb + (size_t)(i * 8) * K_DIM),
          (__attribute__((address_space(3))) void*)(Bs[0] + boff + i * 8 * 64), 16, 0, 0);
    }
    gx += 64; gb += 64;
#pragma unroll
    for (int i = 0; i < 4; ++i) {
      uint4 o;
      asm("v_cvt_pk_bf16_f32 %0, %1, %2" : "=v"(o.x) : "v"(fa[i].x), "v"(fa[i].y));
      asm("v_cvt_pk_bf16_f32 %0, %1, %2" : "=v"(o.y) : "v"(fa[i].z), "v"(fa[i].w));
      asm("v_cvt_pk_bf16_f32 %0, %1, %2" : "=v"(o.z) : "v"(fb4[i].x), "v"(fb4[i].y));
      asm("v_cvt_pk_bf16_f32 %0, %1, %2" : "=v"(o.w) : "v"(fb4[i].z), "v"(fb4[i].w));
      *(uint4*)(As[0] + aoff + i * 8 * 64) = o;
    }
    __syncthreads();
  }

  const int NK = K_PER / 64;  // 32
  for (int kk = 0; kk < NK - 1; ++kk) {
    const int cur = kk & 1, nxt = cur ^ 1;

    // ---- issue tile kk+1 loads (latency hidden under MFMA below) ----
    float4 na[4], nb[4];
#pragma unroll
    for (int i = 0; i < 4; ++i) {
      const float4* p = (const float4*)(gx + (size_t)(i * 8) * K_DIM);
      na[i] = p[0];
      nb[i] = p[1];
    }
#pragma unroll
    for (int i = 0; i < 4; ++i) {
      __builtin_amdgcn_global_load_lds(
          (const __attribute__((address_space(1))) void*)(gb + (size_t)(i * 8) * K_DIM),
          (__attribute__((address_space(3))) void*)(Bs[nxt] + boff + i * 8 * 64), 16, 0, 0);
    }
    gx += 64; gb += 64;

    // ---- compute tile kk from buffer cur ----
    const bf16x8* Av = (const bf16x8*)As[cur];
    const bf16x8* Bv = (const bf16x8*)Bs[cur];
#pragma unroll
    for (int ks = 0; ks < 2; ++ks) {
      bf16x8 af[4], bfr[4];
#pragma unroll
      for (int t = 0; t < 4; ++t) {
        int r = wm * 64 + t * 16 + lane15;
        af[t] = Av[r * 8 + ((ks * 4 + quad) ^ (lane15 & 7))];
      }
#pragma unroll
      for (int u = 0; u < 4; ++u) {
        int r = wn * 64 + u * 16 + lane15;
        bfr[u] = Bv[r * 8 + ((ks * 4 + quad) ^ (lane15 & 7))];
      }
#pragma unroll
      for (int t = 0; t < 4; ++t)
#pragma unroll
        for (int u = 0; u < 4; ++u)
          acc[t][u] = __builtin_amdgcn_mfma_f32_16x16x32_bf16(af[t], bfr[u],
                                                              acc[t][u], 0, 0, 0);
    }

    // ---- convert + write prefetched A into the spare buffer ----
    // (compiler inserts the vmcnt wait on na/nb first use, after the MFMAs)
#pragma unroll
    for (int i = 0; i < 4; ++i) {
      uint4 o;
      asm("v_cvt_pk_bf16_f32 %0, %1, %2" : "=v"(o.x) : "v"(na[i].x), "v"(na[i].y));
      asm("v_cvt_pk_bf16_f32 %0, %1, %2" : "=v"(o.y) : "v"(na[i].z), "v"(na[i].w));
      asm("v_cvt_pk_bf16_f32 %0, %1, %2" : "=v"(o.z) : "v"(nb[i].x), "v"(nb[i].y));
      asm("v_cvt_pk_bf16_f32 %0, %1, %2" : "=v"(o.w) : "v"(nb[i].z), "v"(nb[i].w));
      *(uint4*)(As[nxt] + aoff + i * 8 * 64) = o;
    }
    __syncthreads();  // drains B DMA (in flight across whole compute) + A writes
  }

  // ---- epilogue: compute last tile ----
  {
    const int cur = (NK - 1) & 1;
    const bf16x8* Av = (const bf16x8*)As[cur];
    const bf16x8* Bv = (const bf16x8*)Bs[cur];
#pragma unroll
    for (int ks = 0; ks < 2; ++ks) {
      bf16x8 af[4], bfr[4];
#pragma unroll
      for (int t = 0; t < 4; ++t) {
        int r = wm * 64 + t * 16 + lane15;
        af[t] = Av[r * 8 + ((ks * 4 + quad) ^ (lane15 & 7))];
      }
#pragma unroll
      for (int u = 0; u < 4; ++u) {
        int r = wn * 64 + u * 16 + lane15;
        bfr[u] = Bv[r * 8 + ((ks * 4 + quad) ^ (lane15 & 7))];
      }
#pragma unroll
      for (int t = 0; t < 4; ++t)
#pragma unroll
        for (int u = 0; u < 4; ++u)
          acc[t][u] = __builtin_amdgcn_mfma_f32_16x16x32_bf16(af[t], bfr[u],
                                                              acc[t][u], 0, 0, 0);
    }
  }

  // C/D layout: col = lane&15, row = quad*4 + reg.
  float* cp = part + (size_t)kz * M_DIM * N_POOL;
  const int row_base = bm * 128 + wm * 64;
  const int col_base = bn * 128 + wn * 64;
#pragma unroll
  for (int t = 0; t < 4; ++t)
#pragma unroll
    for (int u = 0; u < 4; ++u) {
      int col = col_base + u * 16 + lane15;
#pragma unroll
      for (int r = 0; r < 4; ++r) {
        int row = row_base + t * 16 + quad * 4 + r;
        cp[(size_t)row * N_POOL + col] = acc[t][u][r];
      }
    }
}

__device__ __forceinline__ float gelu2(float s) {
  float p = s * 0.0625f;  // /16 avgpool
  float t = tanhf(0.7978845608028654f * (p + 0.044715f * p * p * p));
  return p * (1.0f + t);  // gelu_tanh(p) * SCALE(=2)
}

// 4 rows per block (one wave each), float4 reads of part.
__global__ void finalize(const float* __restrict__ part,
                         const float* __restrict__ bpool,
                         float* __restrict__ out) {
  const int w = threadIdx.x >> 6, lane = threadIdx.x & 63;
  const int row = blockIdx.x * 4 + w;
  const float4* bp4 = (const float4*)bpool;
  float mx = -INFINITY;
#pragma unroll
  for (int j = 0; j < 2; ++j) {
    int g4 = lane + j * 64;  // float4 index, 0..127
    float4 s = bp4[g4];
#pragma unroll
    for (int kz = 0; kz < KSPLIT; ++kz) {
      float4 v = ((const float4*)(part + (size_t)kz * M_DIM * N_POOL +
                                  (size_t)row * N_POOL))[g4];
      s.x += v.x; s.y += v.y; s.z += v.z; s.w += v.w;
    }
    mx = fmaxf(mx, fmaxf(fmaxf(gelu2(s.x), gelu2(s.y)),
                         fmaxf(gelu2(s.z), gelu2(s.w))));
  }
#pragma unroll
  for (int sh = 32; sh >= 1; sh >>= 1) mx = fmaxf(mx, __shfl_xor(mx, sh));
  if (lane == 0) out[row] = mx;
}

extern "C" void kernel_launch(void* const* d_in, const int* in_sizes, int n_in,
                              void* d_out, int out_size, void* d_ws, size_t ws_size,
                              hipStream_t stream) {
  const float* x = (const float*)d_in[0];  // [4096,8192]
  const float* W = (const float*)d_in[1];  // [8192,8192]
  const float* b = (const float*)d_in[2];  // [8192]
  float* out = (float*)d_out;              // [4096]

  // Workspace layout (no overlaps; xb eliminated):
  //   Wp    [0,         8388608)    8 MiB  bf16 pooled W
  //   part  [8388608,  41943040)   32 MiB  fp32 split-K partials (KSPLIT=4)
  //   bpool [41943040, 41945088)    2 KiB  fp32 pooled bias
  char* ws = (char*)d_ws;
  unsigned short* Wp = (unsigned short*)ws;
  float* part = (float*)(ws + (size_t)8388608);
  float* bpool = (float*)(ws + (size_t)41943040);

  prep_kernel<<<N_POOL + 1, 256, 0, stream>>>(W, Wp, b, bpool);

  gemm_splitk<<<512, 256, 0, stream>>>(x, Wp, part);

  finalize<<<M_DIM / 4, 256, 0, stream>>>(part, bpool, out);
}

// Round 6
// 483.577 us; speedup vs baseline: 1.0136x; 1.0136x over previous
//
#include <hip/hip_runtime.h>
#include <hip/hip_bf16.h>
#include <cmath>

// y = x[4096,8192] @ W[8192,8192]^T + b; avgpool16 -> gelu_tanh*2 -> rowmax
// Key algebra: avgpool over OUT features commutes with the GEMM:
//   pooled = x @ Wp^T  where Wp[g,:] = sum of W rows 16g..16g+15  (then /16 later)
// -> GEMM is 4096 x 512 x 8192 (16x fewer FLOPs than naive).
// x f32->bf16 conversion fused into GEMM A-staging (reg-staged +
// v_cvt_pk_bf16_f32). This round: BK=128 (two 64-wide K-slices staged per
// barrier) -> 16 iters instead of 32, halving the vmcnt(0)-drain count.
// Single-buffered (R5 dbuf regressed -15us; latency cover was not binding).
#define M_DIM 4096
#define N_POOL 512
#define K_DIM 8192
#define KSPLIT 4
#define K_PER (K_DIM / KSPLIT)  // 2048

typedef __bf16 bf16x8 __attribute__((ext_vector_type(8)));
typedef float floatx4 __attribute__((ext_vector_type(4)));

__device__ __forceinline__ unsigned short f2bf(float f) {
  unsigned int u = __float_as_uint(f);
  return (unsigned short)((u + 0x7fffu + ((u >> 16) & 1u)) >> 16);  // RNE
}

// Prep: blocks [0,512) pool W rows (f32 accum -> bf16 Wp); block 512 pools bias.
__global__ __launch_bounds__(256) void prep_kernel(
    const float* __restrict__ W, unsigned short* __restrict__ Wp,
    const float* __restrict__ b, float* __restrict__ bpool) {
  int bid = blockIdx.x;
  if (bid < N_POOL) {
    int g = bid;
    const float* base = W + (size_t)g * 16 * K_DIM;
    ushort4* out = (ushort4*)(Wp + (size_t)g * K_DIM);
    for (int c4 = threadIdx.x; c4 < K_DIM / 4; c4 += blockDim.x) {
      float4 s = {0.f, 0.f, 0.f, 0.f};
#pragma unroll
      for (int j = 0; j < 16; ++j) {
        float4 v = ((const float4*)(base + (size_t)j * K_DIM))[c4];
        s.x += v.x; s.y += v.y; s.z += v.z; s.w += v.w;
      }
      ushort4 o;
      o.x = f2bf(s.x); o.y = f2bf(s.y); o.z = f2bf(s.z); o.w = f2bf(s.w);
      out[c4] = o;
    }
  } else {
    for (int g = threadIdx.x; g < N_POOL; g += blockDim.x) {
      float s = 0.f;
#pragma unroll
      for (int i = 0; i < 16; ++i) s += b[g * 16 + i];
      bpool[g] = s;
    }
  }
}

// Split-K GEMM: C_part[kz] = x[:, kz*2048:(kz+1)*2048] @ Wp[:, same]^T
// 128x128 tile, BK=128 (2 x 64-wide verified sub-images), 4 waves of 64x64,
// mfma_f32_16x16x32_bf16.
// A: reg-staged from f32 x (fused conversion, XOR-swizzled LDS image).
// B: global_load_lds width=16 with pre-swizzled global source.
// 1D grid of 512, XCD-aware decode: kz pinned to an XCD pair so the
// per-kz Wp slice (1 MiB/XCD) is L2-resident.
__global__ __launch_bounds__(256) void gemm_splitk(
    const float* __restrict__ x,             // [4096][8192] f32
    const unsigned short* __restrict__ wp,   // [512][8192] bf16
    float* __restrict__ part)                // [KSPLIT][4096][512] fp32
{
  // Two 64-col halves, each the proven [128][64] swizzled image.
  __shared__ __align__(16) unsigned short As[2][128 * 64];
  __shared__ __align__(16) unsigned short Bs[2][128 * 64];

  const int tid = threadIdx.x;
  const int L = tid & 63;
  const int w = tid >> 6;
  const int wm = w & 1, wn = w >> 1;
  const int lane15 = L & 15, quad = L >> 4;

  // id -> (kz, bn, bm): xcd = id%8 (HW round-robin), 2 XCDs per kz value.
  const int id = blockIdx.x;
  const int xcd = id & 7;
  const int c = id >> 3;               // 0..63 within XCD
  const int kz = xcd >> 1;             // 0..3
  const int j = (c << 1) | (xcd & 1);  // 0..127 within kz
  const int bn = j & 3, bm = j >> 2;

  const int srow = w * 32 + (L >> 3);          // staging row (i adds 8)
  const int gcol8 = (L & 7) ^ ((L >> 3) & 7);  // swizzled global chunk
  const float* gx = x + (size_t)(bm * 128 + srow) * K_DIM + kz * K_PER + gcol8 * 8;
  const unsigned short* gb = wp + (size_t)(bn * 128 + srow) * K_DIM + kz * K_PER + gcol8 * 8;
  const int aoff = srow * 64 + (L & 7) * 8;    // A LDS write offset (shorts)
  const int boff = (w * 32) * 64;              // B DMA base offset (shorts)

  floatx4 acc[4][4];
#pragma unroll
  for (int t = 0; t < 4; ++t)
#pragma unroll
    for (int u = 0; u < 4; ++u) acc[t][u] = (floatx4)0.f;

  const int NK = K_PER / 128;  // 16
  for (int kk = 0; kk < NK; ++kk) {
    // ---- stage both 64-wide halves, single barrier ----
    float4 fa[2][4], fb4[2][4];
#pragma unroll
    for (int h = 0; h < 2; ++h)
#pragma unroll
      for (int i = 0; i < 4; ++i) {
        const float4* p = (const float4*)(gx + (size_t)(i * 8) * K_DIM + h * 64);
        fa[h][i] = p[0];
        fb4[h][i] = p[1];
      }
#pragma unroll
    for (int h = 0; h < 2; ++h)
#pragma unroll
      for (int i = 0; i < 4; ++i) {
        __builtin_amdgcn_global_load_lds(
            (const __attribute__((address_space(1))) void*)(gb + (size_t)(i * 8) * K_DIM + h * 64),
            (__attribute__((address_space(3))) void*)(Bs[h] + boff + i * 8 * 64), 16, 0, 0);
      }
    gx += 128; gb += 128;
#pragma unroll
    for (int h = 0; h < 2; ++h)
#pragma unroll
      for (int i = 0; i < 4; ++i) {
        uint4 o;
        asm("v_cvt_pk_bf16_f32 %0, %1, %2" : "=v"(o.x) : "v"(fa[h][i].x), "v"(fa[h][i].y));
        asm("v_cvt_pk_bf16_f32 %0, %1, %2" : "=v"(o.y) : "v"(fa[h][i].z), "v"(fa[h][i].w));
        asm("v_cvt_pk_bf16_f32 %0, %1, %2" : "=v"(o.z) : "v"(fb4[h][i].x), "v"(fb4[h][i].y));
        asm("v_cvt_pk_bf16_f32 %0, %1, %2" : "=v"(o.w) : "v"(fb4[h][i].z), "v"(fb4[h][i].w));
        *(uint4*)(As[h] + aoff + (size_t)(i * 8) * 64) = o;
      }
    __syncthreads();  // drains B DMA (vmcnt) + A ds_writes (lgkm)

    // ---- compute 4 ks-slices (2 per half) ----
#pragma unroll
    for (int ks4 = 0; ks4 < 4; ++ks4) {
      const int h = ks4 >> 1, ks = ks4 & 1;
      const bf16x8* Av = (const bf16x8*)As[h];
      const bf16x8* Bv = (const bf16x8*)Bs[h];
      bf16x8 af[4], bfr[4];
#pragma unroll
      for (int t = 0; t < 4; ++t) {
        int r = wm * 64 + t * 16 + lane15;
        af[t] = Av[r * 8 + ((ks * 4 + quad) ^ (lane15 & 7))];
      }
#pragma unroll
      for (int u = 0; u < 4; ++u) {
        int r = wn * 64 + u * 16 + lane15;
        bfr[u] = Bv[r * 8 + ((ks * 4 + quad) ^ (lane15 & 7))];
      }
#pragma unroll
      for (int t = 0; t < 4; ++t)
#pragma unroll
        for (int u = 0; u < 4; ++u)
          acc[t][u] = __builtin_amdgcn_mfma_f32_16x16x32_bf16(af[t], bfr[u],
                                                              acc[t][u], 0, 0, 0);
    }
    __syncthreads();
  }

  // C/D layout: col = lane&15, row = quad*4 + reg.
  float* cp = part + (size_t)kz * M_DIM * N_POOL;
  const int row_base = bm * 128 + wm * 64;
  const int col_base = bn * 128 + wn * 64;
#pragma unroll
  for (int t = 0; t < 4; ++t)
#pragma unroll
    for (int u = 0; u < 4; ++u) {
      int col = col_base + u * 16 + lane15;
#pragma unroll
      for (int r = 0; r < 4; ++r) {
        int row = row_base + t * 16 + quad * 4 + r;
        cp[(size_t)row * N_POOL + col] = acc[t][u][r];
      }
    }
}

__device__ __forceinline__ float gelu2(float s) {
  float p = s * 0.0625f;  // /16 avgpool
  float t = tanhf(0.7978845608028654f * (p + 0.044715f * p * p * p));
  return p * (1.0f + t);  // gelu_tanh(p) * SCALE(=2)
}

// 4 rows per block (one wave each), float4 reads of part.
__global__ void finalize(const float* __restrict__ part,
                         const float* __restrict__ bpool,
                         float* __restrict__ out) {
  const int w = threadIdx.x >> 6, lane = threadIdx.x & 63;
  const int row = blockIdx.x * 4 + w;
  const float4* bp4 = (const float4*)bpool;
  float mx = -INFINITY;
#pragma unroll
  for (int j = 0; j < 2; ++j) {
    int g4 = lane + j * 64;  // float4 index, 0..127
    float4 s = bp4[g4];
#pragma unroll
    for (int kz = 0; kz < KSPLIT; ++kz) {
      float4 v = ((const float4*)(part + (size_t)kz * M_DIM * N_POOL +
                                  (size_t)row * N_POOL))[g4];
      s.x += v.x; s.y += v.y; s.z += v.z; s.w += v.w;
    }
    mx = fmaxf(mx, fmaxf(fmaxf(gelu2(s.x), gelu2(s.y)),
                         fmaxf(gelu2(s.z), gelu2(s.w))));
  }
#pragma unroll
  for (int sh = 32; sh >= 1; sh >>= 1) mx = fmaxf(mx, __shfl_xor(mx, sh));
  if (lane == 0) out[row] = mx;
}

extern "C" void kernel_launch(void* const* d_in, const int* in_sizes, int n_in,
                              void* d_out, int out_size, void* d_ws, size_t ws_size,
                              hipStream_t stream) {
  const float* x = (const float*)d_in[0];  // [4096,8192]
  const float* W = (const float*)d_in[1];  // [8192,8192]
  const float* b = (const float*)d_in[2];  // [8192]
  float* out = (float*)d_out;              // [4096]

  // Workspace layout (no overlaps; xb eliminated):
  //   Wp    [0,         8388608)    8 MiB  bf16 pooled W
  //   part  [8388608,  41943040)   32 MiB  fp32 split-K partials (KSPLIT=4)
  //   bpool [41943040, 41945088)    2 KiB  fp32 pooled bias
  char* ws = (char*)d_ws;
  unsigned short* Wp = (unsigned short*)ws;
  float* part = (float*)(ws + (size_t)8388608);
  float* bpool = (float*)(ws + (size_t)41943040);

  prep_kernel<<<N_POOL + 1, 256, 0, stream>>>(W, Wp, b, bpool);

  gemm_splitk<<<512, 256, 0, stream>>>(x, Wp, part);

  finalize<<<M_DIM / 4, 256, 0, stream>>>(part, bpool, out);
}